// Round 11
// baseline (141.310 us; speedup 1.0000x reference)
//
#include <hip/hip_runtime.h>

#define NVOX (64 * 64 * 64)          // 262144
#define FMU (16 * NVOX)              // u16 elements per packed field (B*C*XYZ)
#define FM (16 * NVOX)               // legacy float field (fallback path)

// Packed field (fast path): u16 per (src,b,c,x,y,z):
//   bit15 = membership; b0-14 = NONZERO side's squared distance
//   (fg if member, bg if not); 32767 = 1e9 sentinel.
// Invariant: member => d_bg == 0; non-member => d_fg == 0; the nonzero
// side's value is >= 1 at every stage (the opposite side owns the zero).
// In-LDS encoding during DT passes: signed float s = member ? -pv : +pv.
//
// FUSED window loop (exact): for the nonzero side, neighbor j contributes
// pv[j]+q if same membership, else exactly q (its same-side value is 0).
// min over opposite neighbors = dopp^2 with dopp from ballot clz/ctz.
// d0 = min(pv, dopp^2); loop over same-side neighbors, break when q >= d.
// Candidate set identical to the reference min-plus => bitwise-exact
// (absmax 0.0 in rounds 2/4/5/6/7/8/9/10).

__device__ __forceinline__ float unpack_val(unsigned short p) {
    int v = p & 0x7fff;
    return (v == 32767) ? 1e9f : (float)v;
}

// ===========================================================================
// FAST PATH
// ===========================================================================

// ---------------------------------------------------------------------------
// Kernel 1: Z (ballot; only the nonzero side's distance is computed) + Y
// (single fused window loop, lanes = y). Block = (src,b,c,x) slab.
// ---------------------------------------------------------------------------
__global__ __launch_bounds__(256) void k_zy2(const float* __restrict__ in,
                                             const int* __restrict__ tg,
                                             unsigned short* __restrict__ f) {
    __shared__ float tile[64 * 65];            // 16.64 KB
    unsigned short* tile16 = (unsigned short*)tile;
    int blk = blockIdx.x;                       // 0..2047
    int src = blk >> 10;
    int s = blk & 1023;
    int b = s >> 9, c = (s >> 6) & 7, x = s & 63;
    int w = threadIdx.x >> 6;                   // wave 0..3
    int lane = threadIdx.x & 63;

    const float* pin = in + (b * 8 + c) * NVOX + x * 4096;
    const int* ptg = tg + b * NVOX + x * 4096;

    // P1 (lanes = z): ballot Z-scan; signed pv -> tile.
#pragma unroll
    for (int k = 0; k < 16; ++k) {
        int y = k * 4 + w;
        bool member;
        if (src == 0) member = pin[y * 64 + lane] > 0.5f;
        else          member = ptg[y * 64 + lane] == c;
        unsigned long long mkA = __ballot(!member);      // non-member bits
        unsigned long long sm = member ? mkA : ~mkA;     // opposite-membership
        unsigned long long sf = sm << (63 - lane), sb = sm >> lane;
        int df = sf ? __builtin_clzll(sf) : 64;
        int db = sb ? __builtin_ctzll(sb) : 64;
        int dz = df < db ? df : db;                      // >= 1 (own bit 0)
        float pv = (dz > 63) ? 1e9f : (float)(dz * dz);
        tile[y * 65 + lane] = member ? -pv : pv;
    }
    __syncthreads();

    // P2 (lanes = y): fused single window loop per column z = k*4+w.
    float rA[16];
    bool mreg[16];
#pragma unroll
    for (int k = 0; k < 16; ++k) {
        int z = k * 4 + w;
        float sv = tile[lane * 65 + z];
        bool m = sv < 0.f;
        float pv = fabsf(sv);
        float msign = m ? -1.f : 1.f;
        unsigned long long mw = __ballot(m);
        unsigned long long xm = m ? ~mw : mw;            // opposite bits
        unsigned long long sf = xm << (63 - lane), sb = xm >> lane;
        int df = sf ? __builtin_clzll(sf) : 64;
        int db = sb ? __builtin_ctzll(sb) : 64;
        int dopp = df < db ? df : db;
        float d = fminf(pv, (dopp > 63) ? 1e9f : (float)(dopp * dopp));
        int q = 1;
        for (int dd = 1; dd <= 63 && (float)q < d; ++dd) {
            int jl = lane - dd, jr = lane + dd;
            float cl = 1e9f, cr = 1e9f;
            if (jl >= 0) {
                float t = tile[jl * 65 + z] * msign;     // >0 iff same side
                cl = (t > 0.f) ? t : 1e9f;
            }
            if (jr < 64) {
                float t = tile[jr * 65 + z] * msign;
                cr = (t > 0.f) ? t : 1e9f;
            }
            d = fminf(d, fminf(cl, cr) + (float)q);
            q += 2 * dd + 1;
        }
        rA[k] = fminf(d, 1e9f);
        mreg[k] = m;
    }
    __syncthreads();

    // P3 (lanes = y): pack u16 into LDS.
#pragma unroll
    for (int k = 0; k < 16; ++k) {
        int z = k * 4 + w;
        int vi = (int)fminf(rA[k], 32767.f);
        tile16[lane * 65 + z] = (unsigned short)((mreg[k] ? 0x8000 : 0) | vi);
    }
    __syncthreads();

    // P4 (lanes = z): coalesced store.
    unsigned short* out = f + (size_t)src * FMU + (b * 8 + c) * NVOX + x * 4096;
#pragma unroll
    for (int k = 0; k < 16; ++k) {
        int y = k * 4 + w;
        out[y * 64 + lane] = tile16[y * 65 + lane];
    }
}

// ---------------------------------------------------------------------------
// Kernel 2: X pass, single fused window loop (lanes = x). Block=(src,b,c,y).
// ---------------------------------------------------------------------------
__global__ __launch_bounds__(256) void k_xdt(unsigned short* __restrict__ f) {
    __shared__ float tile[64 * 65];            // 16.64 KB
    unsigned short* tile16 = (unsigned short*)tile;
    int blk = blockIdx.x;                       // 0..2047
    int src = blk >> 10;
    int s = blk & 1023;
    int b = s >> 9, c = (s >> 6) & 7, y = s & 63;
    int w = threadIdx.x >> 6;
    int lane = threadIdx.x & 63;

    unsigned short* base = f + (size_t)src * FMU + (b * 8 + c) * NVOX + y * 64;

    // P1 (lanes = z): coalesced load + signed unpack.
#pragma unroll
    for (int k = 0; k < 16; ++k) {
        int x = k * 4 + w;
        unsigned short p = base[x * 4096 + lane];
        float v = unpack_val(p);
        tile[x * 65 + lane] = (p & 0x8000) ? -v : v;
    }
    __syncthreads();

    // P2 (lanes = x): fused single window loop per column z = k*4+w.
    float rA[16];
    bool mreg[16];
#pragma unroll
    for (int k = 0; k < 16; ++k) {
        int z = k * 4 + w;
        float sv = tile[lane * 65 + z];
        bool m = sv < 0.f;
        float pv = fabsf(sv);
        float msign = m ? -1.f : 1.f;
        unsigned long long mw = __ballot(m);
        unsigned long long xm = m ? ~mw : mw;
        unsigned long long sf = xm << (63 - lane), sb = xm >> lane;
        int df = sf ? __builtin_clzll(sf) : 64;
        int db = sb ? __builtin_ctzll(sb) : 64;
        int dopp = df < db ? df : db;
        float d = fminf(pv, (dopp > 63) ? 1e9f : (float)(dopp * dopp));
        int q = 1;
        for (int dd = 1; dd <= 63 && (float)q < d; ++dd) {
            int jl = lane - dd, jr = lane + dd;
            float cl = 1e9f, cr = 1e9f;
            if (jl >= 0) {
                float t = tile[jl * 65 + z] * msign;
                cl = (t > 0.f) ? t : 1e9f;
            }
            if (jr < 64) {
                float t = tile[jr * 65 + z] * msign;
                cr = (t > 0.f) ? t : 1e9f;
            }
            d = fminf(d, fminf(cl, cr) + (float)q);
            q += 2 * dd + 1;
        }
        rA[k] = fminf(d, 1e9f);
        mreg[k] = m;
    }
    __syncthreads();

    // P3 (lanes = x): pack.
#pragma unroll
    for (int k = 0; k < 16; ++k) {
        int z = k * 4 + w;
        int vi = (int)fminf(rA[k], 32767.f);
        tile16[lane * 65 + z] = (unsigned short)((mreg[k] ? 0x8000 : 0) | vi);
    }
    __syncthreads();

    // P4 (lanes = z): coalesced store.
#pragma unroll
    for (int k = 0; k < 16; ++k) {
        int x = k * 4 + w;
        base[x * 4096 + lane] = tile16[x * 65 + lane];
    }
}

// ---------------------------------------------------------------------------
// Kernel 3: fused C-axis DT + HD + softmax stats + CE + pred-has-fg.
// ---------------------------------------------------------------------------
__global__ __launch_bounds__(256) void k_chds(const float* __restrict__ in,
                                              const int* __restrict__ tg,
                                              const unsigned short* __restrict__ f,
                                              float* __restrict__ statP,
                                              double* __restrict__ predS,
                                              double* __restrict__ tgtS) {
    __shared__ float part[4][27];
    __shared__ int af;
    if (threadIdx.x == 0) af = 0;
    __syncthreads();

    int blk = blockIdx.x;                       // 0..2047
    int v = blk * 256 + threadIdx.x;
    int b = v >> 18;
    int r = v & (NVOX - 1);
    int t = tg[v];
    int lane = threadIdx.x & 63;
    int wid = threadIdx.x >> 6;

    float xs[8], ex[8];
#pragma unroll
    for (int c = 0; c < 8; ++c) xs[c] = in[(b * 8 + c) * NVOX + r];
    float mx = xs[0];
#pragma unroll
    for (int c = 1; c < 8; ++c) mx = fmaxf(mx, xs[c]);
    float se = 0.f;
#pragma unroll
    for (int c = 0; c < 8; ++c) { ex[c] = expf(xs[c] - mx); se += ex[c]; }
    float inv = 1.f / se;
    float lse = mx + logf(se);
    float xt = xs[0];
#pragma unroll
    for (int c = 1; c < 8; ++c) xt = (t == c) ? xs[c] : xt;

    bool anyP = false;
    float red[17];
    float cnt[8];
#pragma unroll
    for (int c = 0; c < 8; ++c) {
        float p = ex[c] * inv;
        red[c] = p;
        red[8 + c] = (t == c) ? p : 0.f;
        cnt[c] = (float)__popcll(__ballot(t == c));
        anyP = anyP || (xs[c] > 0.5f);
    }
    red[16] = lse - xt;

#pragma unroll
    for (int k = 0; k < 17; ++k) {
        float s = red[k];
        s += __shfl_down(s, 32);
        s += __shfl_down(s, 16);
        s += __shfl_down(s, 8);
        s += __shfl_down(s, 4);
        s += __shfl_down(s, 2);
        s += __shfl_down(s, 1);
        red[k] = s;
    }
    bool wav = __any(anyP);
    if (lane == 0) {
#pragma unroll
        for (int k = 0; k < 8; ++k) part[wid][k] = red[k];
#pragma unroll
        for (int k = 0; k < 8; ++k) part[wid][8 + k] = red[8 + k];
#pragma unroll
        for (int k = 0; k < 8; ++k) part[wid][16 + k] = cnt[k];
        part[wid][24] = red[16];
        if (wav) atomicOr(&af, 1);
    }

    float e2[8];
#pragma unroll
    for (int c = 0; c < 8; ++c) {
        float e = xs[c] - ((t == c) ? 1.f : 0.f);
        e2[c] = e * e;
    }
    float accP = 0.f, accT = 0.f;
#pragma unroll
    for (int src = 0; src < 2; ++src) {
        float fmA[8], fmB[8];
#pragma unroll
        for (int c = 0; c < 8; ++c) {
            unsigned short p = f[(size_t)src * FMU + (b * 8 + c) * NVOX + r];
            float fv = unpack_val(p);
            bool member = (p & 0x8000) != 0;
            fmA[c] = member ? fv : 0.f;
            fmB[c] = member ? 0.f : fv;
        }
        float am = 0.f;
#pragma unroll
        for (int i = 0; i < 8; ++i) {
            float da = 1e9f, db = 1e9f;
#pragma unroll
            for (int j = 0; j < 8; ++j) {
                float q = (float)((i - j) * (i - j));
                da = fminf(da, fmA[j] + q);
                db = fminf(db, fmB[j] + q);
            }
            am += e2[i] * (da + db);
        }
        if (src) accT += am; else accP += am;
    }
#pragma unroll
    for (int off = 32; off >= 1; off >>= 1) {
        accP += __shfl_down(accP, off);
        accT += __shfl_down(accT, off);
    }
    if (lane == 0) { part[wid][25] = accP; part[wid][26] = accT; }
    __syncthreads();

    int j = blk & 1023;
    if (threadIdx.x < 25)
        statP[(b * 26 + threadIdx.x) * 1024 + j] =
            part[0][threadIdx.x] + part[1][threadIdx.x] +
            part[2][threadIdx.x] + part[3][threadIdx.x];
    if (threadIdx.x == 25)
        statP[(b * 26 + 25) * 1024 + j] = af ? 1.f : 0.f;
    if (threadIdx.x == 26)
        predS[blk] = (double)part[0][25] + (double)part[1][25] +
                     (double)part[2][25] + (double)part[3][25];
    if (threadIdx.x == 27)
        tgtS[blk] = (double)part[0][26] + (double)part[1][26] +
                    (double)part[2][26] + (double)part[3][26];
}

// ---------------------------------------------------------------------------
// Kernel 4: reduce partial rows + assemble scalar loss.
// ---------------------------------------------------------------------------
__global__ __launch_bounds__(256) void k_final3(const float* __restrict__ statP,
                                                const double* __restrict__ predS,
                                                const double* __restrict__ tgtS,
                                                float* __restrict__ out) {
    __shared__ float rs[52];
    __shared__ double rd[4];
    int tid = threadIdx.x;
    int w = tid >> 6;
    int lane = tid & 63;

    for (int row = w; row < 52; row += 4) {
        const float* p = statP + row * 1024;
        float s = 0.f;
#pragma unroll
        for (int k = 0; k < 16; ++k) s += p[k * 64 + lane];
        s += __shfl_down(s, 32);
        s += __shfl_down(s, 16);
        s += __shfl_down(s, 8);
        s += __shfl_down(s, 4);
        s += __shfl_down(s, 2);
        s += __shfl_down(s, 1);
        if (lane == 0) rs[row] = s;
    }
    {
        const double* p = (w < 2) ? (predS + w * 1024) : (tgtS + (w - 2) * 1024);
        double s = 0.0;
#pragma unroll
        for (int k = 0; k < 16; ++k) s += p[k * 64 + lane];
        s += __shfl_down(s, 32);
        s += __shfl_down(s, 16);
        s += __shfl_down(s, 8);
        s += __shfl_down(s, 4);
        s += __shfl_down(s, 2);
        s += __shfl_down(s, 1);
        if (lane == 0) rd[w] = s;
    }
    __syncthreads();

    if (tid == 0) {
        bool fP0 = rs[0 * 26 + 25] > 0.f;
        bool fP1 = rs[1 * 26 + 25] > 0.f;
        double h = (fP0 ? rd[0] : 0.0) + (fP1 ? rd[1] : 0.0) + rd[2] + rd[3];
        float dsum = 0.f;
        for (int c = 1; c < 8; ++c) {
            float sc = 0.f;
            for (int b = 0; b < 2; ++b) {
                float S1 = rs[b * 26 + c];
                float S2 = rs[b * 26 + 8 + c];
                float Nc = rs[b * 26 + 16 + c];
                sc += 2.f * S2 / (2.f * S2 + (S1 - S2) + (Nc - S2) + 1e-5f);
            }
            dsum += sc * 0.5f;
        }
        float dice = 1.f - dsum / 7.f;
        float ce = (rs[0 * 26 + 24] + rs[1 * 26 + 24]) / 524288.f;
        out[0] = dice + ce + (float)(h / 4194304.0);
    }
}

// ===========================================================================
// FALLBACK PATH (small workspace) — legacy float-field kernels (absmax 0.0)
// ===========================================================================
__global__ __launch_bounds__(256, 4) void k_stats(const float* __restrict__ in,
                                                  const int* __restrict__ tg,
                                                  float* __restrict__ accF,
                                                  int* __restrict__ flags) {
    int r = blockIdx.x * 256 + threadIdx.x;
    int lane = threadIdx.x & 63;
    int wid = threadIdx.x >> 6;
    __shared__ float part[4][25];
    __shared__ int af;

    for (int b = 0; b < 2; ++b) {
        int t = tg[b * NVOX + r];
        float xs[8];
#pragma unroll
        for (int c = 0; c < 8; ++c) xs[c] = in[(b * 8 + c) * NVOX + r];
        float mx = xs[0];
#pragma unroll
        for (int c = 1; c < 8; ++c) mx = fmaxf(mx, xs[c]);
        float ex[8];
        float se = 0.f;
#pragma unroll
        for (int c = 0; c < 8; ++c) { ex[c] = expf(xs[c] - mx); se += ex[c]; }
        float inv = 1.f / se;
        float lse = mx + logf(se);
        float xt = xs[0];
#pragma unroll
        for (int c = 1; c < 8; ++c) xt = (t == c) ? xs[c] : xt;
        bool anyP = false;
        float red[25];
#pragma unroll
        for (int c = 0; c < 8; ++c) {
            float p = ex[c] * inv;
            red[c] = p;
            red[8 + c] = (t == c) ? p : 0.f;
            red[16 + c] = (t == c) ? 1.f : 0.f;
            anyP = anyP || (xs[c] > 0.5f);
        }
        red[24] = lse - xt;
#pragma unroll
        for (int k = 0; k < 25; ++k) {
            float s = red[k];
            s += __shfl_down(s, 32);
            s += __shfl_down(s, 16);
            s += __shfl_down(s, 8);
            s += __shfl_down(s, 4);
            s += __shfl_down(s, 2);
            s += __shfl_down(s, 1);
            red[k] = s;
        }
        if (threadIdx.x == 0) af = 0;
        __syncthreads();
        bool wav = __any(anyP);
        if (lane == 0) {
#pragma unroll
            for (int k = 0; k < 25; ++k) part[wid][k] = red[k];
            if (wav) atomicOr(&af, 1);
        }
        __syncthreads();
        if (threadIdx.x < 25) {
            float s = part[0][threadIdx.x] + part[1][threadIdx.x] +
                      part[2][threadIdx.x] + part[3][threadIdx.x];
            atomicAdd(&accF[b * 25 + threadIdx.x], s);
        }
        if (threadIdx.x == 0 && af) atomicOr(&flags[b], 1);
        __syncthreads();
    }
}

template <int M0>
__global__ __launch_bounds__(64) void k_mask_zy(const float* __restrict__ in,
                                                const int* __restrict__ tg,
                                                float* __restrict__ f) {
    __shared__ float tile[64 * 65];
    int blk = blockIdx.x;
    int m = M0 + (blk >> 10);
    int s = blk & 1023;
    int b = s >> 9, c = (s >> 6) & 7, x = s & 63;
    int tid = threadIdx.x;

    if ((m & 1) == 0) {
        const float* src = in + (b * 8 + c) * NVOX + x * 4096;
#pragma unroll 8
        for (int k = 0; k < 64; ++k) {
            bool fg = src[k * 64 + tid] > 0.5f;
            bool hot = (m < 2) ? fg : !fg;
            tile[k * 65 + tid] = hot ? 1e9f : 0.f;
        }
    } else {
        const int* src = tg + b * NVOX + x * 4096;
#pragma unroll 8
        for (int k = 0; k < 64; ++k) {
            bool fg = (src[k * 64 + tid] == c);
            bool hot = (m < 2) ? fg : !fg;
            tile[k * 65 + tid] = hot ? 1e9f : 0.f;
        }
    }
    __syncthreads();
    {
        float* row = &tile[tid * 65];
        float g = 1000.f;
#pragma unroll 8
        for (int z = 0; z < 64; ++z) {
            float v = row[z];
            g = (v == 0.f) ? 0.f : g + 1.f;
            row[z] = g;
        }
        g = 1000.f;
#pragma unroll 8
        for (int z = 63; z >= 0; --z) {
            float gf = row[z];
            g = (gf == 0.f) ? 0.f : g + 1.f;
            float d = fminf(gf, g);
            row[z] = (d > 63.f) ? 1e9f : d * d;
        }
    }
    __syncthreads();
    float* out = f + (size_t)(blk >> 10) * FM + (b * 8 + c) * NVOX + x * 4096;
    for (int i = 0; i < 64; ++i) {
        float d0 = tile[i * 65 + tid];
        float d = d0;
        int Ri = (int)sqrtf(d0) + 1;
        Ri = (Ri > 63) ? 63 : Ri;
        for (int dd = 1; dd <= Ri; ++dd) {
            float q = (float)(dd * dd);
            int jl = i - dd, jr = i + dd;
            float cl = (jl >= 0) ? tile[jl * 65 + tid] : 1e9f;
            float cr = (jr < 64) ? tile[jr * 65 + tid] : 1e9f;
            d = fminf(d, fminf(cl, cr) + q);
        }
        out[i * 64 + tid] = fminf(d, 1e9f);
    }
}

template <int M0>
__global__ __launch_bounds__(128, 4) void k_dtx(float* __restrict__ f) {
    __shared__ float wl[128 * 65];
    int blk = blockIdx.x;
    int mi = blk >> 9;
    int s = blk & 511;
    int plane = s >> 5;
    int y0 = (s & 31) * 2;
    int tid = threadIdx.x;
    float* fb = f + (size_t)mi * FM + plane * NVOX + y0 * 64;

#pragma unroll 8
    for (int j = 0; j < 64; ++j) wl[tid * 65 + j] = fb[j * 4096 + tid];

    float* row = &wl[tid * 65];
    for (int i = 0; i < 64; ++i) {
        float d0 = row[i];
        float d = d0;
        int Ri = (int)sqrtf(d0) + 1;
        Ri = (Ri > 63) ? 63 : Ri;
        for (int dd = 1; dd <= Ri; ++dd) {
            float q = (float)(dd * dd);
            int jl = i - dd, jr = i + dd;
            float cl = (jl >= 0) ? row[jl] : 1e9f;
            float cr = (jr < 64) ? row[jr] : 1e9f;
            d = fminf(d, fminf(cl, cr) + q);
        }
        fb[i * 4096 + tid] = fminf(d, 1e9f);
    }
}

template <int M0, int NM>
__global__ __launch_bounds__(256, 4) void k_cdt_hd(const float* __restrict__ in,
                                                   const int* __restrict__ tg,
                                                   const float* __restrict__ f,
                                                   const int* __restrict__ flags,
                                                   double* __restrict__ hd) {
    int v = blockIdx.x * 256 + threadIdx.x;
    int b = v >> 18;
    int r = v & (NVOX - 1);
    int t = tg[v];

    float e2[8];
#pragma unroll
    for (int c = 0; c < 8; ++c) {
        float e = in[(b * 8 + c) * NVOX + r] - ((t == c) ? 1.f : 0.f);
        e2[c] = e * e;
    }
    float acc = 0.f;
#pragma unroll
    for (int mi = 0; mi < NM; ++mi) {
        int m = M0 + mi;
        float fl = (m & 1) ? 1.f : (flags[b] ? 1.f : 0.f);
        float fm[8];
#pragma unroll
        for (int c = 0; c < 8; ++c)
            fm[c] = f[(size_t)mi * FM + (b * 8 + c) * NVOX + r];
        float am = 0.f;
#pragma unroll
        for (int i = 0; i < 8; ++i) {
            float d = 1e9f;
#pragma unroll
            for (int j = 0; j < 8; ++j)
                d = fminf(d, fm[j] + (float)((i - j) * (i - j)));
            am += e2[i] * d;
        }
        acc += fl * am;
    }
    float ssum = acc;
    ssum += __shfl_down(ssum, 32);
    ssum += __shfl_down(ssum, 16);
    ssum += __shfl_down(ssum, 8);
    ssum += __shfl_down(ssum, 4);
    ssum += __shfl_down(ssum, 2);
    ssum += __shfl_down(ssum, 1);
    __shared__ float part[4];
    int lane = threadIdx.x & 63;
    int wid = threadIdx.x >> 6;
    if (lane == 0) part[wid] = ssum;
    __syncthreads();
    if (threadIdx.x == 0)
        atomicAdd(hd, (double)(part[0] + part[1] + part[2] + part[3]));
}

__global__ void k_final(const float* __restrict__ accF,
                        const double* __restrict__ hd,
                        float* __restrict__ out) {
    float dsum = 0.f;
    for (int c = 1; c < 8; ++c) {
        float sc = 0.f;
        for (int b = 0; b < 2; ++b) {
            float S1 = accF[b * 25 + c];
            float S2 = accF[b * 25 + 8 + c];
            float Nc = accF[b * 25 + 16 + c];
            sc += 2.f * S2 / (2.f * S2 + (S1 - S2) + (Nc - S2) + 1e-5f);
        }
        dsum += sc * 0.5f;
    }
    float dice = 1.f - dsum / 7.f;
    float ce = (accF[24] + accF[25 + 24]) / 524288.f;
    float hdv = (float)(hd[0] / 4194304.0);
    out[0] = dice + ce + hdv;
}

template <int M0, int NM>
static void run_chunk(const float* in, const int* tg, float* f,
                      const int* flags, double* hd, hipStream_t stream) {
    k_mask_zy<M0><<<NM * 1024, 64, 0, stream>>>(in, tg, f);
    k_dtx<M0><<<NM * 512, 128, 0, stream>>>(f);
    k_cdt_hd<M0, NM><<<2048, 256, 0, stream>>>(in, tg, f, flags, hd);
}

// ---------------------------------------------------------------------------
extern "C" void kernel_launch(void* const* d_in, const int* in_sizes, int n_in,
                              void* d_out, int out_size, void* d_ws, size_t ws_size,
                              hipStream_t stream) {
    const float* in = (const float*)d_in[0];
    const int* tg = (const int*)d_in[1];
    float* out = (float*)d_out;

    // fast-path layout: packed u16 fields (2 x 8.4 MB), then partials
    size_t offF = (size_t)2 * FMU * 2;           // 16,777,216 bytes
    size_t need_fast = offF + 16384 + 16384 + 52 * 1024 * 4;

    if (ws_size >= need_fast) {
        unsigned short* fu = (unsigned short*)d_ws;
        double* predS = (double*)((char*)d_ws + offF);
        double* tgtS = (double*)((char*)d_ws + offF + 16384);
        float* statP = (float*)((char*)d_ws + offF + 32768);
        k_zy2<<<2048, 256, 0, stream>>>(in, tg, fu);
        k_xdt<<<2048, 256, 0, stream>>>(fu);
        k_chds<<<2048, 256, 0, stream>>>(in, tg, fu, statP, predS, tgtS);
        k_final3<<<1, 256, 0, stream>>>(statP, predS, tgtS, out);
    } else {
        float* f = (float*)d_ws;
        size_t acc_off = ((ws_size - 256) / 256) * 256;
        char* accB = (char*)d_ws + acc_off;
        double* hd = (double*)accB;
        float* accF = (float*)(accB + 8);
        int* flags = (int*)(accB + 208);
        hipMemsetAsync(accB, 0, 256, stream);
        k_stats<<<1024, 256, 0, stream>>>(in, tg, accF, flags);
        int nm_cap = (int)(acc_off / ((size_t)FM * 4));
        if (nm_cap >= 2) {
            run_chunk<0, 2>(in, tg, f, flags, hd, stream);
            run_chunk<2, 2>(in, tg, f, flags, hd, stream);
        } else if (nm_cap >= 1) {
            run_chunk<0, 1>(in, tg, f, flags, hd, stream);
            run_chunk<1, 1>(in, tg, f, flags, hd, stream);
            run_chunk<2, 1>(in, tg, f, flags, hd, stream);
            run_chunk<3, 1>(in, tg, f, flags, hd, stream);
        }
        k_final<<<1, 1, 0, stream>>>(accF, hd, out);
    }
}

// Round 12
// 125.693 us; speedup vs baseline: 1.1242x; 1.1242x over previous
//
#include <hip/hip_runtime.h>

#define NVOX (64 * 64 * 64)          // 262144
#define FMU (16 * NVOX)              // u16 elements per packed field (B*C*XYZ)
#define FM (16 * NVOX)               // legacy float field (fallback path)

// Packed field (fast path): u16 per (src,b,c,x,y,z):
//   bit15 = membership; b0-14 = NONZERO side's squared distance
//   (fg if member, bg if not); 32767 = 1e9 sentinel.
// In-LDS during DT passes: signed float s = member ? -pv : +pv (pv >= 1).
// Window loop (exact): same-side neighbor j contributes pv_j + q; opposite
// neighbor contributes exactly q (its same-side value is 0) -> encoded as
// cl = (t>0) ? t : 0, then d = min(d, min(cl,cr)+q); break when q >= d.
// Candidate set identical to reference min-plus => bitwise-exact
// (absmax 0.0 in rounds 2/4/5/6/7/8/9/10/11).

__device__ __forceinline__ float unpack_val(unsigned short p) {
    int v = p & 0x7fff;
    return (v == 32767) ? 1e9f : (float)v;
}

// ===========================================================================
// FAST PATH
// ===========================================================================

// ---------------------------------------------------------------------------
// Kernel 1: Z (ballot bit-trick) + Y (no-ballot window loop, lanes = y).
// Block = (src,b,c,x) slab. Vectorized uint stores (2 z voxels/lane).
// ---------------------------------------------------------------------------
__global__ __launch_bounds__(256) void k_zy2(const float* __restrict__ in,
                                             const int* __restrict__ tg,
                                             unsigned short* __restrict__ f) {
    __shared__ float tile[64 * 65];            // 16.64 KB
    unsigned short* tile16 = (unsigned short*)tile;   // reused as [64][66]
    int blk = blockIdx.x;                       // 0..2047
    int src = blk >> 10;
    int s = blk & 1023;
    int b = s >> 9, c = (s >> 6) & 7, x = s & 63;
    int w = threadIdx.x >> 6;                   // wave 0..3
    int lane = threadIdx.x & 63;

    const float* pin = in + (b * 8 + c) * NVOX + x * 4096;
    const int* ptg = tg + b * NVOX + x * 4096;

    // P1 (lanes = z): ballot Z-scan; signed pv -> tile.
#pragma unroll
    for (int k = 0; k < 16; ++k) {
        int y = k * 4 + w;
        bool member;
        if (src == 0) member = pin[y * 64 + lane] > 0.5f;
        else          member = ptg[y * 64 + lane] == c;
        unsigned long long mkA = __ballot(!member);      // non-member bits
        unsigned long long sm = member ? mkA : ~mkA;     // opposite bits
        unsigned long long sf = sm << (63 - lane), sb = sm >> lane;
        int df = sf ? __builtin_clzll(sf) : 64;
        int db = sb ? __builtin_ctzll(sb) : 64;
        int dz = df < db ? df : db;                      // >= 1
        float pv = (dz > 63) ? 1e9f : (float)(dz * dz);
        tile[y * 65 + lane] = member ? -pv : pv;
    }
    __syncthreads();

    // P2 (lanes = y): window loop per column z = k*4+w (no ballot preamble).
    float rA[16];
    bool mreg[16];
#pragma unroll
    for (int k = 0; k < 16; ++k) {
        int z = k * 4 + w;
        float sv = tile[lane * 65 + z];
        bool m = sv < 0.f;
        float pv = fabsf(sv);
        float msign = m ? -1.f : 1.f;
        float d = pv;
        int q = 1;
        for (int dd = 1; dd <= 63 && (float)q < d; ++dd) {
            int jl = lane - dd, jr = lane + dd;
            float cl = 1e9f, cr = 1e9f;
            if (jl >= 0) {
                float t = tile[jl * 65 + z] * msign;     // >0 iff same side
                cl = (t > 0.f) ? t : 0.f;                // opposite => +q only
            }
            if (jr < 64) {
                float t = tile[jr * 65 + z] * msign;
                cr = (t > 0.f) ? t : 0.f;
            }
            d = fminf(d, fminf(cl, cr) + (float)q);
            q += 2 * dd + 1;
        }
        rA[k] = fminf(d, 1e9f);
        mreg[k] = m;
    }
    __syncthreads();

    // P3 (lanes = y): pack u16 into stride-66 LDS view.
#pragma unroll
    for (int k = 0; k < 16; ++k) {
        int z = k * 4 + w;
        int vi = (int)fminf(rA[k], 32767.f);
        tile16[lane * 66 + z] = (unsigned short)((mreg[k] ? 0x8000 : 0) | vi);
    }
    __syncthreads();

    // P4: coalesced uint stores (2 z voxels per lane, 2 y rows per wave).
    unsigned int* out32 =
        (unsigned int*)(f + (size_t)src * FMU + (b * 8 + c) * NVOX + x * 4096);
    const unsigned int* t32 = (const unsigned int*)tile16;
    int col = lane & 31;
#pragma unroll
    for (int k = 0; k < 8; ++k) {
        int y = k * 8 + w * 2 + (lane >> 5);
        out32[y * 32 + col] = t32[y * 33 + col];
    }
}

// ---------------------------------------------------------------------------
// Kernel 2: X pass (no-ballot window loop, lanes = x). Block = (src,b,c,y).
// Vectorized uint load/store (2 z voxels/lane).
// ---------------------------------------------------------------------------
__global__ __launch_bounds__(256) void k_xdt(unsigned short* __restrict__ f) {
    __shared__ float tile[64 * 65];            // 16.64 KB
    unsigned short* tile16 = (unsigned short*)tile;   // reused as [64][66]
    int blk = blockIdx.x;                       // 0..2047
    int src = blk >> 10;
    int s = blk & 1023;
    int b = s >> 9, c = (s >> 6) & 7, y = s & 63;
    int w = threadIdx.x >> 6;
    int lane = threadIdx.x & 63;

    unsigned short* base = f + (size_t)src * FMU + (b * 8 + c) * NVOX + y * 64;
    unsigned int* base32 = (unsigned int*)base;
    int col = lane & 31;

    // P1: coalesced uint loads; signed unpack into float tile.
#pragma unroll
    for (int k = 0; k < 8; ++k) {
        int x = k * 8 + w * 2 + (lane >> 5);
        unsigned int pk = base32[x * 2048 + col];
        unsigned short p0 = (unsigned short)(pk & 0xffff);
        unsigned short p1 = (unsigned short)(pk >> 16);
        float v0 = unpack_val(p0), v1 = unpack_val(p1);
        int zz = col * 2;
        tile[x * 65 + zz] = (p0 & 0x8000) ? -v0 : v0;
        tile[x * 65 + zz + 1] = (p1 & 0x8000) ? -v1 : v1;
    }
    __syncthreads();

    // P2 (lanes = x): window loop per column z = k*4+w.
    float rA[16];
    bool mreg[16];
#pragma unroll
    for (int k = 0; k < 16; ++k) {
        int z = k * 4 + w;
        float sv = tile[lane * 65 + z];
        bool m = sv < 0.f;
        float pv = fabsf(sv);
        float msign = m ? -1.f : 1.f;
        float d = pv;
        int q = 1;
        for (int dd = 1; dd <= 63 && (float)q < d; ++dd) {
            int jl = lane - dd, jr = lane + dd;
            float cl = 1e9f, cr = 1e9f;
            if (jl >= 0) {
                float t = tile[jl * 65 + z] * msign;
                cl = (t > 0.f) ? t : 0.f;
            }
            if (jr < 64) {
                float t = tile[jr * 65 + z] * msign;
                cr = (t > 0.f) ? t : 0.f;
            }
            d = fminf(d, fminf(cl, cr) + (float)q);
            q += 2 * dd + 1;
        }
        rA[k] = fminf(d, 1e9f);
        mreg[k] = m;
    }
    __syncthreads();

    // P3 (lanes = x): pack into stride-66 LDS view.
#pragma unroll
    for (int k = 0; k < 16; ++k) {
        int z = k * 4 + w;
        int vi = (int)fminf(rA[k], 32767.f);
        tile16[lane * 66 + z] = (unsigned short)((mreg[k] ? 0x8000 : 0) | vi);
    }
    __syncthreads();

    // P4: coalesced uint stores.
    const unsigned int* t32 = (const unsigned int*)tile16;
#pragma unroll
    for (int k = 0; k < 8; ++k) {
        int x = k * 8 + w * 2 + (lane >> 5);
        base32[x * 2048 + col] = t32[x * 33 + col];
    }
}

// ---------------------------------------------------------------------------
// Kernel 3: fused C-axis DT + HD + softmax stats + CE + pred-has-fg.
// TWO voxels per thread (float2/int2/uint loads); stats accumulated across
// both voxels before the shfl chains; class counts via ballot+popcount.
// ---------------------------------------------------------------------------
__global__ __launch_bounds__(256) void k_chds(const float* __restrict__ in,
                                              const int* __restrict__ tg,
                                              const unsigned short* __restrict__ f,
                                              float* __restrict__ statP,
                                              double* __restrict__ predS,
                                              double* __restrict__ tgtS) {
    __shared__ float part[4][27];
    __shared__ int af;
    if (threadIdx.x == 0) af = 0;
    __syncthreads();

    int blk = blockIdx.x;                       // 0..1023
    int v = blk * 512 + threadIdx.x * 2;
    int b = v >> 18;
    int r = v & (NVOX - 1);
    int lane = threadIdx.x & 63;
    int wid = threadIdx.x >> 6;

    int2 tt = *(const int2*)&tg[v];
    float2 xv[8];
#pragma unroll
    for (int c = 0; c < 8; ++c)
        xv[c] = *(const float2*)&in[(b * 8 + c) * NVOX + r];

    float red[17];
#pragma unroll
    for (int k = 0; k < 17; ++k) red[k] = 0.f;
    bool anyP = false;

#pragma unroll
    for (int u = 0; u < 2; ++u) {
        int t = u ? tt.y : tt.x;
        float xs[8];
#pragma unroll
        for (int c = 0; c < 8; ++c) xs[c] = u ? xv[c].y : xv[c].x;
        float mx = xs[0];
#pragma unroll
        for (int c = 1; c < 8; ++c) mx = fmaxf(mx, xs[c]);
        float ex[8];
        float se = 0.f;
#pragma unroll
        for (int c = 0; c < 8; ++c) { ex[c] = expf(xs[c] - mx); se += ex[c]; }
        float inv = 1.f / se;
        float lse = mx + logf(se);
        float xt = xs[0];
#pragma unroll
        for (int c = 1; c < 8; ++c) xt = (t == c) ? xs[c] : xt;
#pragma unroll
        for (int c = 0; c < 8; ++c) {
            float p = ex[c] * inv;
            red[c] += p;
            red[8 + c] += (t == c) ? p : 0.f;
            anyP = anyP || (xs[c] > 0.5f);
        }
        red[16] += lse - xt;
    }

    float cnt[8];
#pragma unroll
    for (int c = 0; c < 8; ++c)
        cnt[c] = (float)(__popcll(__ballot(tt.x == c)) +
                         __popcll(__ballot(tt.y == c)));

#pragma unroll
    for (int k = 0; k < 17; ++k) {
        float s = red[k];
        s += __shfl_down(s, 32);
        s += __shfl_down(s, 16);
        s += __shfl_down(s, 8);
        s += __shfl_down(s, 4);
        s += __shfl_down(s, 2);
        s += __shfl_down(s, 1);
        red[k] = s;
    }
    bool wav = __any(anyP);
    if (lane == 0) {
#pragma unroll
        for (int k = 0; k < 8; ++k) part[wid][k] = red[k];
#pragma unroll
        for (int k = 0; k < 8; ++k) part[wid][8 + k] = red[8 + k];
#pragma unroll
        for (int k = 0; k < 8; ++k) part[wid][16 + k] = cnt[k];
        part[wid][24] = red[16];
        if (wav) atomicOr(&af, 1);
    }

    // HD: load both voxels' packed fields once (uint per src,c).
    unsigned int fw[16];
#pragma unroll
    for (int src = 0; src < 2; ++src)
#pragma unroll
        for (int c = 0; c < 8; ++c)
            fw[src * 8 + c] =
                *(const unsigned int*)&f[(size_t)src * FMU + (b * 8 + c) * NVOX + r];

    float accP = 0.f, accT = 0.f;
#pragma unroll
    for (int u = 0; u < 2; ++u) {
        int t = u ? tt.y : tt.x;
        float e2[8];
#pragma unroll
        for (int c = 0; c < 8; ++c) {
            float x = u ? xv[c].y : xv[c].x;
            float e = x - ((t == c) ? 1.f : 0.f);
            e2[c] = e * e;
        }
#pragma unroll
        for (int src = 0; src < 2; ++src) {
            float fmA[8], fmB[8];
#pragma unroll
            for (int c = 0; c < 8; ++c) {
                unsigned int pk = fw[src * 8 + c];
                unsigned short p = (unsigned short)(u ? (pk >> 16) : (pk & 0xffff));
                float fv = unpack_val(p);
                bool member = (p & 0x8000) != 0;
                fmA[c] = member ? fv : 0.f;
                fmB[c] = member ? 0.f : fv;
            }
            float am = 0.f;
#pragma unroll
            for (int i = 0; i < 8; ++i) {
                float da = 1e9f, db = 1e9f;
#pragma unroll
                for (int j = 0; j < 8; ++j) {
                    float q = (float)((i - j) * (i - j));
                    da = fminf(da, fmA[j] + q);
                    db = fminf(db, fmB[j] + q);
                }
                am += e2[i] * (da + db);
            }
            if (src) accT += am; else accP += am;
        }
    }
#pragma unroll
    for (int off = 32; off >= 1; off >>= 1) {
        accP += __shfl_down(accP, off);
        accT += __shfl_down(accT, off);
    }
    if (lane == 0) { part[wid][25] = accP; part[wid][26] = accT; }
    __syncthreads();

    int j = blk & 511;
    if (threadIdx.x < 25)
        statP[(b * 26 + threadIdx.x) * 512 + j] =
            part[0][threadIdx.x] + part[1][threadIdx.x] +
            part[2][threadIdx.x] + part[3][threadIdx.x];
    if (threadIdx.x == 25)
        statP[(b * 26 + 25) * 512 + j] = af ? 1.f : 0.f;
    if (threadIdx.x == 26)
        predS[blk] = (double)part[0][25] + (double)part[1][25] +
                     (double)part[2][25] + (double)part[3][25];
    if (threadIdx.x == 27)
        tgtS[blk] = (double)part[0][26] + (double)part[1][26] +
                    (double)part[2][26] + (double)part[3][26];
}

// ---------------------------------------------------------------------------
// Kernel 4: reduce partial rows (512 wide) + assemble scalar loss.
// ---------------------------------------------------------------------------
__global__ __launch_bounds__(256) void k_final3(const float* __restrict__ statP,
                                                const double* __restrict__ predS,
                                                const double* __restrict__ tgtS,
                                                float* __restrict__ out) {
    __shared__ float rs[52];
    __shared__ double rd[4];
    int tid = threadIdx.x;
    int w = tid >> 6;
    int lane = tid & 63;

    for (int row = w; row < 52; row += 4) {
        const float* p = statP + row * 512;
        float s = 0.f;
#pragma unroll
        for (int k = 0; k < 8; ++k) s += p[k * 64 + lane];
        s += __shfl_down(s, 32);
        s += __shfl_down(s, 16);
        s += __shfl_down(s, 8);
        s += __shfl_down(s, 4);
        s += __shfl_down(s, 2);
        s += __shfl_down(s, 1);
        if (lane == 0) rs[row] = s;
    }
    {
        const double* p = (w < 2) ? (predS + w * 512) : (tgtS + (w - 2) * 512);
        double s = 0.0;
#pragma unroll
        for (int k = 0; k < 8; ++k) s += p[k * 64 + lane];
        s += __shfl_down(s, 32);
        s += __shfl_down(s, 16);
        s += __shfl_down(s, 8);
        s += __shfl_down(s, 4);
        s += __shfl_down(s, 2);
        s += __shfl_down(s, 1);
        if (lane == 0) rd[w] = s;
    }
    __syncthreads();

    if (tid == 0) {
        bool fP0 = rs[0 * 26 + 25] > 0.f;
        bool fP1 = rs[1 * 26 + 25] > 0.f;
        double h = (fP0 ? rd[0] : 0.0) + (fP1 ? rd[1] : 0.0) + rd[2] + rd[3];
        float dsum = 0.f;
        for (int c = 1; c < 8; ++c) {
            float sc = 0.f;
            for (int b = 0; b < 2; ++b) {
                float S1 = rs[b * 26 + c];
                float S2 = rs[b * 26 + 8 + c];
                float Nc = rs[b * 26 + 16 + c];
                sc += 2.f * S2 / (2.f * S2 + (S1 - S2) + (Nc - S2) + 1e-5f);
            }
            dsum += sc * 0.5f;
        }
        float dice = 1.f - dsum / 7.f;
        float ce = (rs[0 * 26 + 24] + rs[1 * 26 + 24]) / 524288.f;
        out[0] = dice + ce + (float)(h / 4194304.0);
    }
}

// ===========================================================================
// FALLBACK PATH (small workspace) — legacy float-field kernels (absmax 0.0)
// ===========================================================================
__global__ __launch_bounds__(256, 4) void k_stats(const float* __restrict__ in,
                                                  const int* __restrict__ tg,
                                                  float* __restrict__ accF,
                                                  int* __restrict__ flags) {
    int r = blockIdx.x * 256 + threadIdx.x;
    int lane = threadIdx.x & 63;
    int wid = threadIdx.x >> 6;
    __shared__ float part[4][25];
    __shared__ int af;

    for (int b = 0; b < 2; ++b) {
        int t = tg[b * NVOX + r];
        float xs[8];
#pragma unroll
        for (int c = 0; c < 8; ++c) xs[c] = in[(b * 8 + c) * NVOX + r];
        float mx = xs[0];
#pragma unroll
        for (int c = 1; c < 8; ++c) mx = fmaxf(mx, xs[c]);
        float ex[8];
        float se = 0.f;
#pragma unroll
        for (int c = 0; c < 8; ++c) { ex[c] = expf(xs[c] - mx); se += ex[c]; }
        float inv = 1.f / se;
        float lse = mx + logf(se);
        float xt = xs[0];
#pragma unroll
        for (int c = 1; c < 8; ++c) xt = (t == c) ? xs[c] : xt;
        bool anyP = false;
        float red[25];
#pragma unroll
        for (int c = 0; c < 8; ++c) {
            float p = ex[c] * inv;
            red[c] = p;
            red[8 + c] = (t == c) ? p : 0.f;
            red[16 + c] = (t == c) ? 1.f : 0.f;
            anyP = anyP || (xs[c] > 0.5f);
        }
        red[24] = lse - xt;
#pragma unroll
        for (int k = 0; k < 25; ++k) {
            float s = red[k];
            s += __shfl_down(s, 32);
            s += __shfl_down(s, 16);
            s += __shfl_down(s, 8);
            s += __shfl_down(s, 4);
            s += __shfl_down(s, 2);
            s += __shfl_down(s, 1);
            red[k] = s;
        }
        if (threadIdx.x == 0) af = 0;
        __syncthreads();
        bool wav = __any(anyP);
        if (lane == 0) {
#pragma unroll
            for (int k = 0; k < 25; ++k) part[wid][k] = red[k];
            if (wav) atomicOr(&af, 1);
        }
        __syncthreads();
        if (threadIdx.x < 25) {
            float s = part[0][threadIdx.x] + part[1][threadIdx.x] +
                      part[2][threadIdx.x] + part[3][threadIdx.x];
            atomicAdd(&accF[b * 25 + threadIdx.x], s);
        }
        if (threadIdx.x == 0 && af) atomicOr(&flags[b], 1);
        __syncthreads();
    }
}

template <int M0>
__global__ __launch_bounds__(64) void k_mask_zy(const float* __restrict__ in,
                                                const int* __restrict__ tg,
                                                float* __restrict__ f) {
    __shared__ float tile[64 * 65];
    int blk = blockIdx.x;
    int m = M0 + (blk >> 10);
    int s = blk & 1023;
    int b = s >> 9, c = (s >> 6) & 7, x = s & 63;
    int tid = threadIdx.x;

    if ((m & 1) == 0) {
        const float* src = in + (b * 8 + c) * NVOX + x * 4096;
#pragma unroll 8
        for (int k = 0; k < 64; ++k) {
            bool fg = src[k * 64 + tid] > 0.5f;
            bool hot = (m < 2) ? fg : !fg;
            tile[k * 65 + tid] = hot ? 1e9f : 0.f;
        }
    } else {
        const int* src = tg + b * NVOX + x * 4096;
#pragma unroll 8
        for (int k = 0; k < 64; ++k) {
            bool fg = (src[k * 64 + tid] == c);
            bool hot = (m < 2) ? fg : !fg;
            tile[k * 65 + tid] = hot ? 1e9f : 0.f;
        }
    }
    __syncthreads();
    {
        float* row = &tile[tid * 65];
        float g = 1000.f;
#pragma unroll 8
        for (int z = 0; z < 64; ++z) {
            float v = row[z];
            g = (v == 0.f) ? 0.f : g + 1.f;
            row[z] = g;
        }
        g = 1000.f;
#pragma unroll 8
        for (int z = 63; z >= 0; --z) {
            float gf = row[z];
            g = (gf == 0.f) ? 0.f : g + 1.f;
            float d = fminf(gf, g);
            row[z] = (d > 63.f) ? 1e9f : d * d;
        }
    }
    __syncthreads();
    float* out = f + (size_t)(blk >> 10) * FM + (b * 8 + c) * NVOX + x * 4096;
    for (int i = 0; i < 64; ++i) {
        float d0 = tile[i * 65 + tid];
        float d = d0;
        int Ri = (int)sqrtf(d0) + 1;
        Ri = (Ri > 63) ? 63 : Ri;
        for (int dd = 1; dd <= Ri; ++dd) {
            float q = (float)(dd * dd);
            int jl = i - dd, jr = i + dd;
            float cl = (jl >= 0) ? tile[jl * 65 + tid] : 1e9f;
            float cr = (jr < 64) ? tile[jr * 65 + tid] : 1e9f;
            d = fminf(d, fminf(cl, cr) + q);
        }
        out[i * 64 + tid] = fminf(d, 1e9f);
    }
}

template <int M0>
__global__ __launch_bounds__(128, 4) void k_dtx(float* __restrict__ f) {
    __shared__ float wl[128 * 65];
    int blk = blockIdx.x;
    int mi = blk >> 9;
    int s = blk & 511;
    int plane = s >> 5;
    int y0 = (s & 31) * 2;
    int tid = threadIdx.x;
    float* fb = f + (size_t)mi * FM + plane * NVOX + y0 * 64;

#pragma unroll 8
    for (int j = 0; j < 64; ++j) wl[tid * 65 + j] = fb[j * 4096 + tid];

    float* row = &wl[tid * 65];
    for (int i = 0; i < 64; ++i) {
        float d0 = row[i];
        float d = d0;
        int Ri = (int)sqrtf(d0) + 1;
        Ri = (Ri > 63) ? 63 : Ri;
        for (int dd = 1; dd <= Ri; ++dd) {
            float q = (float)(dd * dd);
            int jl = i - dd, jr = i + dd;
            float cl = (jl >= 0) ? row[jl] : 1e9f;
            float cr = (jr < 64) ? row[jr] : 1e9f;
            d = fminf(d, fminf(cl, cr) + q);
        }
        fb[i * 4096 + tid] = fminf(d, 1e9f);
    }
}

template <int M0, int NM>
__global__ __launch_bounds__(256, 4) void k_cdt_hd(const float* __restrict__ in,
                                                   const int* __restrict__ tg,
                                                   const float* __restrict__ f,
                                                   const int* __restrict__ flags,
                                                   double* __restrict__ hd) {
    int v = blockIdx.x * 256 + threadIdx.x;
    int b = v >> 18;
    int r = v & (NVOX - 1);
    int t = tg[v];

    float e2[8];
#pragma unroll
    for (int c = 0; c < 8; ++c) {
        float e = in[(b * 8 + c) * NVOX + r] - ((t == c) ? 1.f : 0.f);
        e2[c] = e * e;
    }
    float acc = 0.f;
#pragma unroll
    for (int mi = 0; mi < NM; ++mi) {
        int m = M0 + mi;
        float fl = (m & 1) ? 1.f : (flags[b] ? 1.f : 0.f);
        float fm[8];
#pragma unroll
        for (int c = 0; c < 8; ++c)
            fm[c] = f[(size_t)mi * FM + (b * 8 + c) * NVOX + r];
        float am = 0.f;
#pragma unroll
        for (int i = 0; i < 8; ++i) {
            float d = 1e9f;
#pragma unroll
            for (int j = 0; j < 8; ++j)
                d = fminf(d, fm[j] + (float)((i - j) * (i - j)));
            am += e2[i] * d;
        }
        acc += fl * am;
    }
    float ssum = acc;
    ssum += __shfl_down(ssum, 32);
    ssum += __shfl_down(ssum, 16);
    ssum += __shfl_down(ssum, 8);
    ssum += __shfl_down(ssum, 4);
    ssum += __shfl_down(ssum, 2);
    ssum += __shfl_down(ssum, 1);
    __shared__ float part[4];
    int lane = threadIdx.x & 63;
    int wid = threadIdx.x >> 6;
    if (lane == 0) part[wid] = ssum;
    __syncthreads();
    if (threadIdx.x == 0)
        atomicAdd(hd, (double)(part[0] + part[1] + part[2] + part[3]));
}

__global__ void k_final(const float* __restrict__ accF,
                        const double* __restrict__ hd,
                        float* __restrict__ out) {
    float dsum = 0.f;
    for (int c = 1; c < 8; ++c) {
        float sc = 0.f;
        for (int b = 0; b < 2; ++b) {
            float S1 = accF[b * 25 + c];
            float S2 = accF[b * 25 + 8 + c];
            float Nc = accF[b * 25 + 16 + c];
            sc += 2.f * S2 / (2.f * S2 + (S1 - S2) + (Nc - S2) + 1e-5f);
        }
        dsum += sc * 0.5f;
    }
    float dice = 1.f - dsum / 7.f;
    float ce = (accF[24] + accF[25 + 24]) / 524288.f;
    float hdv = (float)(hd[0] / 4194304.0);
    out[0] = dice + ce + hdv;
}

template <int M0, int NM>
static void run_chunk(const float* in, const int* tg, float* f,
                      const int* flags, double* hd, hipStream_t stream) {
    k_mask_zy<M0><<<NM * 1024, 64, 0, stream>>>(in, tg, f);
    k_dtx<M0><<<NM * 512, 128, 0, stream>>>(f);
    k_cdt_hd<M0, NM><<<2048, 256, 0, stream>>>(in, tg, f, flags, hd);
}

// ---------------------------------------------------------------------------
extern "C" void kernel_launch(void* const* d_in, const int* in_sizes, int n_in,
                              void* d_out, int out_size, void* d_ws, size_t ws_size,
                              hipStream_t stream) {
    const float* in = (const float*)d_in[0];
    const int* tg = (const int*)d_in[1];
    float* out = (float*)d_out;

    // fast-path layout: packed u16 fields (2 x 8.4 MB), then partials
    size_t offF = (size_t)2 * FMU * 2;           // 16,777,216 bytes
    size_t need_fast = offF + 8192 + 8192 + 52 * 512 * 4;

    if (ws_size >= need_fast) {
        unsigned short* fu = (unsigned short*)d_ws;
        double* predS = (double*)((char*)d_ws + offF);
        double* tgtS = (double*)((char*)d_ws + offF + 8192);
        float* statP = (float*)((char*)d_ws + offF + 16384);
        k_zy2<<<2048, 256, 0, stream>>>(in, tg, fu);
        k_xdt<<<2048, 256, 0, stream>>>(fu);
        k_chds<<<1024, 256, 0, stream>>>(in, tg, fu, statP, predS, tgtS);
        k_final3<<<1, 256, 0, stream>>>(statP, predS, tgtS, out);
    } else {
        float* f = (float*)d_ws;
        size_t acc_off = ((ws_size - 256) / 256) * 256;
        char* accB = (char*)d_ws + acc_off;
        double* hd = (double*)accB;
        float* accF = (float*)(accB + 8);
        int* flags = (int*)(accB + 208);
        hipMemsetAsync(accB, 0, 256, stream);
        k_stats<<<1024, 256, 0, stream>>>(in, tg, accF, flags);
        int nm_cap = (int)(acc_off / ((size_t)FM * 4));
        if (nm_cap >= 2) {
            run_chunk<0, 2>(in, tg, f, flags, hd, stream);
            run_chunk<2, 2>(in, tg, f, flags, hd, stream);
        } else if (nm_cap >= 1) {
            run_chunk<0, 1>(in, tg, f, flags, hd, stream);
            run_chunk<1, 1>(in, tg, f, flags, hd, stream);
            run_chunk<2, 1>(in, tg, f, flags, hd, stream);
            run_chunk<3, 1>(in, tg, f, flags, hd, stream);
        }
        k_final<<<1, 1, 0, stream>>>(accF, hd, out);
    }
}

// Round 13
// 125.318 us; speedup vs baseline: 1.1276x; 1.0030x over previous
//
#include <hip/hip_runtime.h>

#define NVOX (64 * 64 * 64)          // 262144
#define FMU (16 * NVOX)              // u16 elements per packed field (B*C*XYZ)
#define FM (16 * NVOX)               // legacy float field (fallback path)

// Packed field (fast path): u16 per (src,b,c,x,y,z):
//   bit15 = membership; b0-14 = NONZERO side's squared distance
//   (fg if member, bg if not); 32767 = 1e9 sentinel.
// In-LDS during DT passes: signed float s = member ? -pv : +pv (pv >= 1).
// Window loop (exact): same-side neighbor contributes pv_j + q; opposite
// neighbor contributes exactly q. XOR-sign trick: cand =
// fmax(as_float(as_int(sv_j) ^ sgn_i), 0) = same-side ? pv_j : 0.
// Candidate set identical to reference min-plus => bitwise-exact
// (absmax 0.0 in rounds 2/4/5/6/7/8/9/10/11/12).

__device__ __forceinline__ float unpack_val(unsigned short p) {
    int v = p & 0x7fff;
    return (v == 32767) ? 1e9f : (float)v;
}

// ===========================================================================
// FAST PATH
// ===========================================================================

// ---------------------------------------------------------------------------
// Kernel 1: Z (ballot bit-trick) + Y (XOR-sign window loop, lanes = y).
// Block = (src,b,c,x) slab. Vectorized uint stores (2 z voxels/lane).
// ---------------------------------------------------------------------------
__global__ __launch_bounds__(256) void k_zy2(const float* __restrict__ in,
                                             const int* __restrict__ tg,
                                             unsigned short* __restrict__ f) {
    __shared__ float tile[64 * 65];            // 16.64 KB
    unsigned short* tile16 = (unsigned short*)tile;   // reused as [64][66]
    int blk = blockIdx.x;                       // 0..2047
    int src = blk >> 10;
    int s = blk & 1023;
    int b = s >> 9, c = (s >> 6) & 7, x = s & 63;
    int w = threadIdx.x >> 6;                   // wave 0..3
    int lane = threadIdx.x & 63;

    const float* pin = in + (b * 8 + c) * NVOX + x * 4096;
    const int* ptg = tg + b * NVOX + x * 4096;

    // P1 (lanes = z): ballot Z-scan; signed pv -> tile.
#pragma unroll
    for (int k = 0; k < 16; ++k) {
        int y = k * 4 + w;
        bool member;
        if (src == 0) member = pin[y * 64 + lane] > 0.5f;
        else          member = ptg[y * 64 + lane] == c;
        unsigned long long mkA = __ballot(!member);      // non-member bits
        unsigned long long sm = member ? mkA : ~mkA;     // opposite bits
        unsigned long long sf = sm << (63 - lane), sb = sm >> lane;
        int df = sf ? __builtin_clzll(sf) : 64;
        int db = sb ? __builtin_ctzll(sb) : 64;
        int dz = df < db ? df : db;                      // >= 1
        float pv = (dz > 63) ? 1e9f : (float)(dz * dz);
        tile[y * 65 + lane] = member ? -pv : pv;
    }
    __syncthreads();

    // P2 (lanes = y): XOR-sign window loop per column z = k*4+w.
    float rA[16];
    bool mreg[16];
#pragma unroll
    for (int k = 0; k < 16; ++k) {
        int z = k * 4 + w;
        const float* pc = &tile[lane * 65 + z];
        float sv = pc[0];
        bool m = sv < 0.f;
        int sgn = m ? (int)0x80000000 : 0;
        float d = fabsf(sv);
        float qf = 1.f, step = 3.f;
        for (int dd = 1; dd <= 63 && qf < d; ++dd) {
            float cl = 1e9f, cr = 1e9f;
            if (lane - dd >= 0) {
                int t = __float_as_int(pc[-dd * 65]) ^ sgn;
                cl = fmaxf(__int_as_float(t), 0.f);      // same-side? pv : 0
            }
            if (lane + dd < 64) {
                int t = __float_as_int(pc[dd * 65]) ^ sgn;
                cr = fmaxf(__int_as_float(t), 0.f);
            }
            d = fminf(d, fminf(cl, cr) + qf);
            qf += step; step += 2.f;
        }
        rA[k] = fminf(d, 1e9f);
        mreg[k] = m;
    }
    __syncthreads();

    // P3 (lanes = y): pack u16 into stride-66 LDS view.
#pragma unroll
    for (int k = 0; k < 16; ++k) {
        int z = k * 4 + w;
        int vi = (int)fminf(rA[k], 32767.f);
        tile16[lane * 66 + z] = (unsigned short)((mreg[k] ? 0x8000 : 0) | vi);
    }
    __syncthreads();

    // P4: coalesced uint stores (2 z voxels per lane, 2 y rows per wave).
    unsigned int* out32 =
        (unsigned int*)(f + (size_t)src * FMU + (b * 8 + c) * NVOX + x * 4096);
    const unsigned int* t32 = (const unsigned int*)tile16;
    int col = lane & 31;
#pragma unroll
    for (int k = 0; k < 8; ++k) {
        int y = k * 8 + w * 2 + (lane >> 5);
        out32[y * 32 + col] = t32[y * 33 + col];
    }
}

// ---------------------------------------------------------------------------
// Kernel 2: X pass (XOR-sign window loop, lanes = x). Block = (src,b,c,y).
// Vectorized uint load/store (2 z voxels/lane).
// ---------------------------------------------------------------------------
__global__ __launch_bounds__(256) void k_xdt(unsigned short* __restrict__ f) {
    __shared__ float tile[64 * 65];            // 16.64 KB
    unsigned short* tile16 = (unsigned short*)tile;   // reused as [64][66]
    int blk = blockIdx.x;                       // 0..2047
    int src = blk >> 10;
    int s = blk & 1023;
    int b = s >> 9, c = (s >> 6) & 7, y = s & 63;
    int w = threadIdx.x >> 6;
    int lane = threadIdx.x & 63;

    unsigned short* base = f + (size_t)src * FMU + (b * 8 + c) * NVOX + y * 64;
    unsigned int* base32 = (unsigned int*)base;
    int col = lane & 31;

    // P1: coalesced uint loads; signed unpack into float tile.
#pragma unroll
    for (int k = 0; k < 8; ++k) {
        int x = k * 8 + w * 2 + (lane >> 5);
        unsigned int pk = base32[x * 2048 + col];
        unsigned short p0 = (unsigned short)(pk & 0xffff);
        unsigned short p1 = (unsigned short)(pk >> 16);
        float v0 = unpack_val(p0), v1 = unpack_val(p1);
        int zz = col * 2;
        tile[x * 65 + zz] = (p0 & 0x8000) ? -v0 : v0;
        tile[x * 65 + zz + 1] = (p1 & 0x8000) ? -v1 : v1;
    }
    __syncthreads();

    // P2 (lanes = x): XOR-sign window loop per column z = k*4+w.
    float rA[16];
    bool mreg[16];
#pragma unroll
    for (int k = 0; k < 16; ++k) {
        int z = k * 4 + w;
        const float* pc = &tile[lane * 65 + z];
        float sv = pc[0];
        bool m = sv < 0.f;
        int sgn = m ? (int)0x80000000 : 0;
        float d = fabsf(sv);
        float qf = 1.f, step = 3.f;
        for (int dd = 1; dd <= 63 && qf < d; ++dd) {
            float cl = 1e9f, cr = 1e9f;
            if (lane - dd >= 0) {
                int t = __float_as_int(pc[-dd * 65]) ^ sgn;
                cl = fmaxf(__int_as_float(t), 0.f);
            }
            if (lane + dd < 64) {
                int t = __float_as_int(pc[dd * 65]) ^ sgn;
                cr = fmaxf(__int_as_float(t), 0.f);
            }
            d = fminf(d, fminf(cl, cr) + qf);
            qf += step; step += 2.f;
        }
        rA[k] = fminf(d, 1e9f);
        mreg[k] = m;
    }
    __syncthreads();

    // P3 (lanes = x): pack into stride-66 LDS view.
#pragma unroll
    for (int k = 0; k < 16; ++k) {
        int z = k * 4 + w;
        int vi = (int)fminf(rA[k], 32767.f);
        tile16[lane * 66 + z] = (unsigned short)((mreg[k] ? 0x8000 : 0) | vi);
    }
    __syncthreads();

    // P4: coalesced uint stores.
    const unsigned int* t32 = (const unsigned int*)tile16;
#pragma unroll
    for (int k = 0; k < 8; ++k) {
        int x = k * 8 + w * 2 + (lane >> 5);
        base32[x * 2048 + col] = t32[x * 33 + col];
    }
}

// ---------------------------------------------------------------------------
// Kernel 3: fused C-axis DT + HD + softmax stats + CE + pred-has-fg.
// TWO voxels per thread (float2/int2/uint loads); stats accumulated across
// both voxels before the shfl chains; class counts via ballot+popcount.
// ---------------------------------------------------------------------------
__global__ __launch_bounds__(256) void k_chds(const float* __restrict__ in,
                                              const int* __restrict__ tg,
                                              const unsigned short* __restrict__ f,
                                              float* __restrict__ statP,
                                              double* __restrict__ predS,
                                              double* __restrict__ tgtS) {
    __shared__ float part[4][27];
    __shared__ int af;
    if (threadIdx.x == 0) af = 0;
    __syncthreads();

    int blk = blockIdx.x;                       // 0..1023
    int v = blk * 512 + threadIdx.x * 2;
    int b = v >> 18;
    int r = v & (NVOX - 1);
    int lane = threadIdx.x & 63;
    int wid = threadIdx.x >> 6;

    int2 tt = *(const int2*)&tg[v];
    float2 xv[8];
#pragma unroll
    for (int c = 0; c < 8; ++c)
        xv[c] = *(const float2*)&in[(b * 8 + c) * NVOX + r];

    float red[17];
#pragma unroll
    for (int k = 0; k < 17; ++k) red[k] = 0.f;
    bool anyP = false;

#pragma unroll
    for (int u = 0; u < 2; ++u) {
        int t = u ? tt.y : tt.x;
        float xs[8];
#pragma unroll
        for (int c = 0; c < 8; ++c) xs[c] = u ? xv[c].y : xv[c].x;
        float mx = xs[0];
#pragma unroll
        for (int c = 1; c < 8; ++c) mx = fmaxf(mx, xs[c]);
        float ex[8];
        float se = 0.f;
#pragma unroll
        for (int c = 0; c < 8; ++c) { ex[c] = expf(xs[c] - mx); se += ex[c]; }
        float inv = 1.f / se;
        float lse = mx + logf(se);
        float xt = xs[0];
#pragma unroll
        for (int c = 1; c < 8; ++c) xt = (t == c) ? xs[c] : xt;
#pragma unroll
        for (int c = 0; c < 8; ++c) {
            float p = ex[c] * inv;
            red[c] += p;
            red[8 + c] += (t == c) ? p : 0.f;
            anyP = anyP || (xs[c] > 0.5f);
        }
        red[16] += lse - xt;
    }

    float cnt[8];
#pragma unroll
    for (int c = 0; c < 8; ++c)
        cnt[c] = (float)(__popcll(__ballot(tt.x == c)) +
                         __popcll(__ballot(tt.y == c)));

#pragma unroll
    for (int k = 0; k < 17; ++k) {
        float s = red[k];
        s += __shfl_down(s, 32);
        s += __shfl_down(s, 16);
        s += __shfl_down(s, 8);
        s += __shfl_down(s, 4);
        s += __shfl_down(s, 2);
        s += __shfl_down(s, 1);
        red[k] = s;
    }
    bool wav = __any(anyP);
    if (lane == 0) {
#pragma unroll
        for (int k = 0; k < 8; ++k) part[wid][k] = red[k];
#pragma unroll
        for (int k = 0; k < 8; ++k) part[wid][8 + k] = red[8 + k];
#pragma unroll
        for (int k = 0; k < 8; ++k) part[wid][16 + k] = cnt[k];
        part[wid][24] = red[16];
        if (wav) atomicOr(&af, 1);
    }

    // HD: load both voxels' packed fields once (uint per src,c).
    unsigned int fw[16];
#pragma unroll
    for (int src = 0; src < 2; ++src)
#pragma unroll
        for (int c = 0; c < 8; ++c)
            fw[src * 8 + c] =
                *(const unsigned int*)&f[(size_t)src * FMU + (b * 8 + c) * NVOX + r];

    float accP = 0.f, accT = 0.f;
#pragma unroll
    for (int u = 0; u < 2; ++u) {
        int t = u ? tt.y : tt.x;
        float e2[8];
#pragma unroll
        for (int c = 0; c < 8; ++c) {
            float x = u ? xv[c].y : xv[c].x;
            float e = x - ((t == c) ? 1.f : 0.f);
            e2[c] = e * e;
        }
#pragma unroll
        for (int src = 0; src < 2; ++src) {
            float fmA[8], fmB[8];
#pragma unroll
            for (int c = 0; c < 8; ++c) {
                unsigned int pk = fw[src * 8 + c];
                unsigned short p = (unsigned short)(u ? (pk >> 16) : (pk & 0xffff));
                float fv = unpack_val(p);
                bool member = (p & 0x8000) != 0;
                fmA[c] = member ? fv : 0.f;
                fmB[c] = member ? 0.f : fv;
            }
            float am = 0.f;
#pragma unroll
            for (int i = 0; i < 8; ++i) {
                float da = 1e9f, db = 1e9f;
#pragma unroll
                for (int j = 0; j < 8; ++j) {
                    float q = (float)((i - j) * (i - j));
                    da = fminf(da, fmA[j] + q);
                    db = fminf(db, fmB[j] + q);
                }
                am += e2[i] * (da + db);
            }
            if (src) accT += am; else accP += am;
        }
    }
#pragma unroll
    for (int off = 32; off >= 1; off >>= 1) {
        accP += __shfl_down(accP, off);
        accT += __shfl_down(accT, off);
    }
    if (lane == 0) { part[wid][25] = accP; part[wid][26] = accT; }
    __syncthreads();

    int j = blk & 511;
    if (threadIdx.x < 25)
        statP[(b * 26 + threadIdx.x) * 512 + j] =
            part[0][threadIdx.x] + part[1][threadIdx.x] +
            part[2][threadIdx.x] + part[3][threadIdx.x];
    if (threadIdx.x == 25)
        statP[(b * 26 + 25) * 512 + j] = af ? 1.f : 0.f;
    if (threadIdx.x == 26)
        predS[blk] = (double)part[0][25] + (double)part[1][25] +
                     (double)part[2][25] + (double)part[3][25];
    if (threadIdx.x == 27)
        tgtS[blk] = (double)part[0][26] + (double)part[1][26] +
                    (double)part[2][26] + (double)part[3][26];
}

// ---------------------------------------------------------------------------
// Kernel 4: reduce partial rows (512 wide) + assemble scalar loss.
// ---------------------------------------------------------------------------
__global__ __launch_bounds__(256) void k_final3(const float* __restrict__ statP,
                                                const double* __restrict__ predS,
                                                const double* __restrict__ tgtS,
                                                float* __restrict__ out) {
    __shared__ float rs[52];
    __shared__ double rd[4];
    int tid = threadIdx.x;
    int w = tid >> 6;
    int lane = tid & 63;

    for (int row = w; row < 52; row += 4) {
        const float* p = statP + row * 512;
        float s = 0.f;
#pragma unroll
        for (int k = 0; k < 8; ++k) s += p[k * 64 + lane];
        s += __shfl_down(s, 32);
        s += __shfl_down(s, 16);
        s += __shfl_down(s, 8);
        s += __shfl_down(s, 4);
        s += __shfl_down(s, 2);
        s += __shfl_down(s, 1);
        if (lane == 0) rs[row] = s;
    }
    {
        const double* p = (w < 2) ? (predS + w * 512) : (tgtS + (w - 2) * 512);
        double s = 0.0;
#pragma unroll
        for (int k = 0; k < 8; ++k) s += p[k * 64 + lane];
        s += __shfl_down(s, 32);
        s += __shfl_down(s, 16);
        s += __shfl_down(s, 8);
        s += __shfl_down(s, 4);
        s += __shfl_down(s, 2);
        s += __shfl_down(s, 1);
        if (lane == 0) rd[w] = s;
    }
    __syncthreads();

    if (tid == 0) {
        bool fP0 = rs[0 * 26 + 25] > 0.f;
        bool fP1 = rs[1 * 26 + 25] > 0.f;
        double h = (fP0 ? rd[0] : 0.0) + (fP1 ? rd[1] : 0.0) + rd[2] + rd[3];
        float dsum = 0.f;
        for (int c = 1; c < 8; ++c) {
            float sc = 0.f;
            for (int b = 0; b < 2; ++b) {
                float S1 = rs[b * 26 + c];
                float S2 = rs[b * 26 + 8 + c];
                float Nc = rs[b * 26 + 16 + c];
                sc += 2.f * S2 / (2.f * S2 + (S1 - S2) + (Nc - S2) + 1e-5f);
            }
            dsum += sc * 0.5f;
        }
        float dice = 1.f - dsum / 7.f;
        float ce = (rs[0 * 26 + 24] + rs[1 * 26 + 24]) / 524288.f;
        out[0] = dice + ce + (float)(h / 4194304.0);
    }
}

// ===========================================================================
// FALLBACK PATH (small workspace) — legacy float-field kernels (absmax 0.0)
// ===========================================================================
__global__ __launch_bounds__(256, 4) void k_stats(const float* __restrict__ in,
                                                  const int* __restrict__ tg,
                                                  float* __restrict__ accF,
                                                  int* __restrict__ flags) {
    int r = blockIdx.x * 256 + threadIdx.x;
    int lane = threadIdx.x & 63;
    int wid = threadIdx.x >> 6;
    __shared__ float part[4][25];
    __shared__ int af;

    for (int b = 0; b < 2; ++b) {
        int t = tg[b * NVOX + r];
        float xs[8];
#pragma unroll
        for (int c = 0; c < 8; ++c) xs[c] = in[(b * 8 + c) * NVOX + r];
        float mx = xs[0];
#pragma unroll
        for (int c = 1; c < 8; ++c) mx = fmaxf(mx, xs[c]);
        float ex[8];
        float se = 0.f;
#pragma unroll
        for (int c = 0; c < 8; ++c) { ex[c] = expf(xs[c] - mx); se += ex[c]; }
        float inv = 1.f / se;
        float lse = mx + logf(se);
        float xt = xs[0];
#pragma unroll
        for (int c = 1; c < 8; ++c) xt = (t == c) ? xs[c] : xt;
        bool anyP = false;
        float red[25];
#pragma unroll
        for (int c = 0; c < 8; ++c) {
            float p = ex[c] * inv;
            red[c] = p;
            red[8 + c] = (t == c) ? p : 0.f;
            red[16 + c] = (t == c) ? 1.f : 0.f;
            anyP = anyP || (xs[c] > 0.5f);
        }
        red[24] = lse - xt;
#pragma unroll
        for (int k = 0; k < 25; ++k) {
            float s = red[k];
            s += __shfl_down(s, 32);
            s += __shfl_down(s, 16);
            s += __shfl_down(s, 8);
            s += __shfl_down(s, 4);
            s += __shfl_down(s, 2);
            s += __shfl_down(s, 1);
            red[k] = s;
        }
        if (threadIdx.x == 0) af = 0;
        __syncthreads();
        bool wav = __any(anyP);
        if (lane == 0) {
#pragma unroll
            for (int k = 0; k < 25; ++k) part[wid][k] = red[k];
            if (wav) atomicOr(&af, 1);
        }
        __syncthreads();
        if (threadIdx.x < 25) {
            float s = part[0][threadIdx.x] + part[1][threadIdx.x] +
                      part[2][threadIdx.x] + part[3][threadIdx.x];
            atomicAdd(&accF[b * 25 + threadIdx.x], s);
        }
        if (threadIdx.x == 0 && af) atomicOr(&flags[b], 1);
        __syncthreads();
    }
}

template <int M0>
__global__ __launch_bounds__(64) void k_mask_zy(const float* __restrict__ in,
                                                const int* __restrict__ tg,
                                                float* __restrict__ f) {
    __shared__ float tile[64 * 65];
    int blk = blockIdx.x;
    int m = M0 + (blk >> 10);
    int s = blk & 1023;
    int b = s >> 9, c = (s >> 6) & 7, x = s & 63;
    int tid = threadIdx.x;

    if ((m & 1) == 0) {
        const float* src = in + (b * 8 + c) * NVOX + x * 4096;
#pragma unroll 8
        for (int k = 0; k < 64; ++k) {
            bool fg = src[k * 64 + tid] > 0.5f;
            bool hot = (m < 2) ? fg : !fg;
            tile[k * 65 + tid] = hot ? 1e9f : 0.f;
        }
    } else {
        const int* src = tg + b * NVOX + x * 4096;
#pragma unroll 8
        for (int k = 0; k < 64; ++k) {
            bool fg = (src[k * 64 + tid] == c);
            bool hot = (m < 2) ? fg : !fg;
            tile[k * 65 + tid] = hot ? 1e9f : 0.f;
        }
    }
    __syncthreads();
    {
        float* row = &tile[tid * 65];
        float g = 1000.f;
#pragma unroll 8
        for (int z = 0; z < 64; ++z) {
            float v = row[z];
            g = (v == 0.f) ? 0.f : g + 1.f;
            row[z] = g;
        }
        g = 1000.f;
#pragma unroll 8
        for (int z = 63; z >= 0; --z) {
            float gf = row[z];
            g = (gf == 0.f) ? 0.f : g + 1.f;
            float d = fminf(gf, g);
            row[z] = (d > 63.f) ? 1e9f : d * d;
        }
    }
    __syncthreads();
    float* out = f + (size_t)(blk >> 10) * FM + (b * 8 + c) * NVOX + x * 4096;
    for (int i = 0; i < 64; ++i) {
        float d0 = tile[i * 65 + tid];
        float d = d0;
        int Ri = (int)sqrtf(d0) + 1;
        Ri = (Ri > 63) ? 63 : Ri;
        for (int dd = 1; dd <= Ri; ++dd) {
            float q = (float)(dd * dd);
            int jl = i - dd, jr = i + dd;
            float cl = (jl >= 0) ? tile[jl * 65 + tid] : 1e9f;
            float cr = (jr < 64) ? tile[jr * 65 + tid] : 1e9f;
            d = fminf(d, fminf(cl, cr) + q);
        }
        out[i * 64 + tid] = fminf(d, 1e9f);
    }
}

template <int M0>
__global__ __launch_bounds__(128, 4) void k_dtx(float* __restrict__ f) {
    __shared__ float wl[128 * 65];
    int blk = blockIdx.x;
    int mi = blk >> 9;
    int s = blk & 511;
    int plane = s >> 5;
    int y0 = (s & 31) * 2;
    int tid = threadIdx.x;
    float* fb = f + (size_t)mi * FM + plane * NVOX + y0 * 64;

#pragma unroll 8
    for (int j = 0; j < 64; ++j) wl[tid * 65 + j] = fb[j * 4096 + tid];

    float* row = &wl[tid * 65];
    for (int i = 0; i < 64; ++i) {
        float d0 = row[i];
        float d = d0;
        int Ri = (int)sqrtf(d0) + 1;
        Ri = (Ri > 63) ? 63 : Ri;
        for (int dd = 1; dd <= Ri; ++dd) {
            float q = (float)(dd * dd);
            int jl = i - dd, jr = i + dd;
            float cl = (jl >= 0) ? row[jl] : 1e9f;
            float cr = (jr < 64) ? row[jr] : 1e9f;
            d = fminf(d, fminf(cl, cr) + q);
        }
        fb[i * 4096 + tid] = fminf(d, 1e9f);
    }
}

template <int M0, int NM>
__global__ __launch_bounds__(256, 4) void k_cdt_hd(const float* __restrict__ in,
                                                   const int* __restrict__ tg,
                                                   const float* __restrict__ f,
                                                   const int* __restrict__ flags,
                                                   double* __restrict__ hd) {
    int v = blockIdx.x * 256 + threadIdx.x;
    int b = v >> 18;
    int r = v & (NVOX - 1);
    int t = tg[v];

    float e2[8];
#pragma unroll
    for (int c = 0; c < 8; ++c) {
        float e = in[(b * 8 + c) * NVOX + r] - ((t == c) ? 1.f : 0.f);
        e2[c] = e * e;
    }
    float acc = 0.f;
#pragma unroll
    for (int mi = 0; mi < NM; ++mi) {
        int m = M0 + mi;
        float fl = (m & 1) ? 1.f : (flags[b] ? 1.f : 0.f);
        float fm[8];
#pragma unroll
        for (int c = 0; c < 8; ++c)
            fm[c] = f[(size_t)mi * FM + (b * 8 + c) * NVOX + r];
        float am = 0.f;
#pragma unroll
        for (int i = 0; i < 8; ++i) {
            float d = 1e9f;
#pragma unroll
            for (int j = 0; j < 8; ++j)
                d = fminf(d, fm[j] + (float)((i - j) * (i - j)));
            am += e2[i] * d;
        }
        acc += fl * am;
    }
    float ssum = acc;
    ssum += __shfl_down(ssum, 32);
    ssum += __shfl_down(ssum, 16);
    ssum += __shfl_down(ssum, 8);
    ssum += __shfl_down(ssum, 4);
    ssum += __shfl_down(ssum, 2);
    ssum += __shfl_down(ssum, 1);
    __shared__ float part[4];
    int lane = threadIdx.x & 63;
    int wid = threadIdx.x >> 6;
    if (lane == 0) part[wid] = ssum;
    __syncthreads();
    if (threadIdx.x == 0)
        atomicAdd(hd, (double)(part[0] + part[1] + part[2] + part[3]));
}

__global__ void k_final(const float* __restrict__ accF,
                        const double* __restrict__ hd,
                        float* __restrict__ out) {
    float dsum = 0.f;
    for (int c = 1; c < 8; ++c) {
        float sc = 0.f;
        for (int b = 0; b < 2; ++b) {
            float S1 = accF[b * 25 + c];
            float S2 = accF[b * 25 + 8 + c];
            float Nc = accF[b * 25 + 16 + c];
            sc += 2.f * S2 / (2.f * S2 + (S1 - S2) + (Nc - S2) + 1e-5f);
        }
        dsum += sc * 0.5f;
    }
    float dice = 1.f - dsum / 7.f;
    float ce = (accF[24] + accF[25 + 24]) / 524288.f;
    float hdv = (float)(hd[0] / 4194304.0);
    out[0] = dice + ce + hdv;
}

template <int M0, int NM>
static void run_chunk(const float* in, const int* tg, float* f,
                      const int* flags, double* hd, hipStream_t stream) {
    k_mask_zy<M0><<<NM * 1024, 64, 0, stream>>>(in, tg, f);
    k_dtx<M0><<<NM * 512, 128, 0, stream>>>(f);
    k_cdt_hd<M0, NM><<<2048, 256, 0, stream>>>(in, tg, f, flags, hd);
}

// ---------------------------------------------------------------------------
extern "C" void kernel_launch(void* const* d_in, const int* in_sizes, int n_in,
                              void* d_out, int out_size, void* d_ws, size_t ws_size,
                              hipStream_t stream) {
    const float* in = (const float*)d_in[0];
    const int* tg = (const int*)d_in[1];
    float* out = (float*)d_out;

    // fast-path layout: packed u16 fields (2 x 8.4 MB), then partials
    size_t offF = (size_t)2 * FMU * 2;           // 16,777,216 bytes
    size_t need_fast = offF + 8192 + 8192 + 52 * 512 * 4;

    if (ws_size >= need_fast) {
        unsigned short* fu = (unsigned short*)d_ws;
        double* predS = (double*)((char*)d_ws + offF);
        double* tgtS = (double*)((char*)d_ws + offF + 8192);
        float* statP = (float*)((char*)d_ws + offF + 16384);
        k_zy2<<<2048, 256, 0, stream>>>(in, tg, fu);
        k_xdt<<<2048, 256, 0, stream>>>(fu);
        k_chds<<<1024, 256, 0, stream>>>(in, tg, fu, statP, predS, tgtS);
        k_final3<<<1, 256, 0, stream>>>(statP, predS, tgtS, out);
    } else {
        float* f = (float*)d_ws;
        size_t acc_off = ((ws_size - 256) / 256) * 256;
        char* accB = (char*)d_ws + acc_off;
        double* hd = (double*)accB;
        float* accF = (float*)(accB + 8);
        int* flags = (int*)(accB + 208);
        hipMemsetAsync(accB, 0, 256, stream);
        k_stats<<<1024, 256, 0, stream>>>(in, tg, accF, flags);
        int nm_cap = (int)(acc_off / ((size_t)FM * 4));
        if (nm_cap >= 2) {
            run_chunk<0, 2>(in, tg, f, flags, hd, stream);
            run_chunk<2, 2>(in, tg, f, flags, hd, stream);
        } else if (nm_cap >= 1) {
            run_chunk<0, 1>(in, tg, f, flags, hd, stream);
            run_chunk<1, 1>(in, tg, f, flags, hd, stream);
            run_chunk<2, 1>(in, tg, f, flags, hd, stream);
            run_chunk<3, 1>(in, tg, f, flags, hd, stream);
        }
        k_final<<<1, 1, 0, stream>>>(accF, hd, out);
    }
}